// Round 4
// baseline (918.024 us; speedup 1.0000x reference)
//
#include <hip/hip_runtime.h>
#include <hip/hip_bf16.h>
#include <stdint.h>

#define F_IN 768
#define H_DIM 128
#define BSHIFT 6            // 64 nodes per bucket

typedef __attribute__((ext_vector_type(8))) short short8;
typedef __attribute__((ext_vector_type(4))) float floatx4;

__device__ __forceinline__ unsigned short f2bf(float f) {
    union { float f; unsigned u; } v; v.f = f;
    unsigned r = v.u + 0x7fff + ((v.u >> 16) & 1);   // RNE
    return (unsigned short)(r >> 16);
}
__device__ __forceinline__ float bflo(unsigned u) {
    union { unsigned u; float f; } v; v.u = u << 16;
    return v.f;
}
__device__ __forceinline__ float bfhi(unsigned u) {
    union { unsigned u; float f; } v; v.u = u & 0xffff0000u;
    return v.f;
}

// ---------- CSR build ----------
__global__ void k_init_cnt(int* __restrict__ cnt, int N) {
    int i = blockIdx.x * blockDim.x + threadIdx.x;
    if (i < N) cnt[i] = 1;  // self loop
}

__global__ void k_count(const int* __restrict__ ei, int E, int N, int* __restrict__ cnt) {
    int e = blockIdx.x * blockDim.x + threadIdx.x;
    if (e < E) {
        int d = ei[E + e];
        d = min(max(d, 0), N - 1);
        atomicAdd(&cnt[d], 1);
    }
}

__global__ __launch_bounds__(1024) void k_scan(const int* __restrict__ cnt,
                                               int* __restrict__ offs, int N) {
    __shared__ int sdata[1024];
    int t = threadIdx.x;
    int chunk = (N + 1023) >> 10;
    int beg = t * chunk, end = min(beg + chunk, N);
    int s = 0;
    for (int i = beg; i < end; i++) s += cnt[i];
    sdata[t] = s;
    __syncthreads();
    for (int off = 1; off < 1024; off <<= 1) {
        int v = (t >= off) ? sdata[t - off] : 0;
        __syncthreads();
        sdata[t] += v;
        __syncthreads();
    }
    int excl = sdata[t] - s;
    int run = excl;
    for (int i = beg; i < end; i++) { offs[i] = run; run += cnt[i]; }
    if (t == 1023) offs[N] = sdata[1023];
}

__global__ void k_prep(const int* __restrict__ cnt, const int* __restrict__ offs,
                       int* __restrict__ csr, int* __restrict__ cursor,
                       float* __restrict__ dis, int N) {
    int i = blockIdx.x * blockDim.x + threadIdx.x;
    if (i < N) {
        int o = offs[i];
        csr[o] = i;             // self loop entry first
        cursor[i] = o + 1;
        dis[i] = rsqrtf((float)cnt[i]);
    }
}

// bucket bases: edges-only exclusive prefix at bucket boundaries
__global__ void k_bbase(const int* __restrict__ offs, int* __restrict__ ebase,
                        int* __restrict__ bcur, int N, int NB) {
    int b = blockIdx.x * blockDim.x + threadIdx.x;
    if (b <= NB) {
        int lo = min(b << BSHIFT, N);
        int v = offs[lo] - lo;
        ebase[b] = v;
        if (b < NB) bcur[b] = v;
    }
}

// bin edges by dst bucket; per-bucket windows advance sequentially
__global__ void k_bin(const int* __restrict__ ei, int E, int N,
                      int* __restrict__ bcur, uint2* __restrict__ binned) {
    int e = blockIdx.x * blockDim.x + threadIdx.x;
    if (e < E) {
        int s = ei[e], d = ei[E + e];
        s = min(max(s, 0), N - 1);
        d = min(max(d, 0), N - 1);
        int b = d >> BSHIFT;
        int pos = atomicAdd(&bcur[b], 1);
        binned[pos] = make_uint2((unsigned)s, (unsigned)d);
    }
}

// one block per bucket: scatter confined to ~8.5KB csr window (L2-local)
__global__ __launch_bounds__(256) void k_fill2(const uint2* __restrict__ binned,
                                               const int* __restrict__ ebase,
                                               int* __restrict__ cursor,
                                               int* __restrict__ csr) {
    int b = blockIdx.x;
    int beg = ebase[b], end = ebase[b + 1];
    for (int j = beg + threadIdx.x; j < end; j += 256) {
        uint2 sd = binned[j];
        int pos = atomicAdd(&cursor[sd.y], 1);
        csr[pos] = (int)sd.x;
    }
}

// ---------- W1 -> bf16 in MFMA B-fragment order ----------
// W1B[f][kb][lane][j]  (f<8, kb<24, lane<64, j<8), flat idx = ((f*24+kb)*64+lane)*8+j
// maps to B[k][n] with n = f*16 + (lane&15), k = kb*32 + (lane>>4)*8 + j
__global__ void k_w1b(const float* __restrict__ W1, unsigned short* __restrict__ W1B) {
    int t = blockIdx.x * blockDim.x + threadIdx.x;   // one thread per 8-elem group
    if (t >= 8 * 24 * 64) return;
    int lane = t & 63;
    int kb = (t >> 6) % 24;
    int f  = (t >> 6) / 24;
    int r = lane & 15, quad = lane >> 4;
    int col = f * 16 + r;
    int k0 = kb * 32 + quad * 8;
    unsigned short* o = W1B + (size_t)t * 8;
#pragma unroll
    for (int j = 0; j < 8; j++) o[j] = f2bf(W1[(size_t)(k0 + j) * H_DIM + col]);
}

// ---------- GEMM1: h = bf16(x @ W1), MFMA 16x16x32 bf16 ----------
#define A_STRIDE 776
__global__ __launch_bounds__(256) void k_gemm1(const float* __restrict__ x,
                                               const unsigned short* __restrict__ W1B,
                                               unsigned short* __restrict__ h, int N) {
    __shared__ unsigned short As[16 * A_STRIDE];
    int rowblk = blockIdx.x * 16;

#pragma unroll
    for (int j = 0; j < 12; j++) {
        int seg = j * 256 + threadIdx.x;          // 0..3071, 192 segs/row
        int row = seg / 192;
        int col = (seg - row * 192) * 4;
        int srow = min(rowblk + row, N - 1);
        floatx4 v = *(const floatx4*)(x + (size_t)srow * F_IN + col);
        uint2 w;
        w.x = (unsigned)f2bf(v[0]) | ((unsigned)f2bf(v[1]) << 16);
        w.y = (unsigned)f2bf(v[2]) | ((unsigned)f2bf(v[3]) << 16);
        *(uint2*)(&As[row * A_STRIDE + col]) = w;
    }
    __syncthreads();

    int wv = threadIdx.x >> 6;
    int lane = threadIdx.x & 63;
    int quad = lane >> 4;
    int r = lane & 15;

    const unsigned short* bp = W1B + ((size_t)(2 * wv) * 24 * 512) + (size_t)lane * 8;
    const unsigned short* ap = As + r * A_STRIDE + quad * 8;

    floatx4 acc0 = (floatx4){0.f, 0.f, 0.f, 0.f};
    floatx4 acc1 = (floatx4){0.f, 0.f, 0.f, 0.f};
#pragma unroll
    for (int kb = 0; kb < 24; kb++) {
        short8 af = *(const short8*)(ap + kb * 32);
        short8 b0 = *(const short8*)(bp + kb * 512);
        short8 b1 = *(const short8*)(bp + 12288 + kb * 512);   // f+1 block
        acc0 = __builtin_amdgcn_mfma_f32_16x16x32_bf16(af, b0, acc0, 0, 0, 0);
        acc1 = __builtin_amdgcn_mfma_f32_16x16x32_bf16(af, b1, acc1, 0, 0, 0);
    }
    int c0 = (2 * wv) * 16 + r, c1 = (2 * wv + 1) * 16 + r;
#pragma unroll
    for (int i = 0; i < 4; i++) {
        int orow = rowblk + quad * 4 + i;
        if (orow < N) {
            h[(size_t)orow * H_DIM + c0] = f2bf(acc0[i]);
            h[(size_t)orow * H_DIM + c1] = f2bf(acc1[i]);
        }
    }
}

// ---------- Aggregation layer 1 + bias + relu + @W2 fused ----------
__global__ __launch_bounds__(256) void k_agg1(const unsigned short* __restrict__ h,
                                              const int* __restrict__ csr,
                                              const int* __restrict__ offs,
                                              const float* __restrict__ dis,
                                              const float* __restrict__ b1,
                                              const float* __restrict__ W2,
                                              float* __restrict__ h2, int N) {
    int wv = (blockIdx.x * blockDim.x + threadIdx.x) >> 6;
    if (wv >= N) return;
    int lane = threadIdx.x & 63;
    int c = lane & 31;
    int p = lane >> 5;
    int beg = offs[wv], end = offs[wv + 1];
    float a0 = 0.f, a1 = 0.f, a2 = 0.f, a3 = 0.f;
    for (int j0 = beg; j0 < end; j0 += 64) {
        int idx = j0 + lane;
        bool valid = idx < end;
        int u = csr[valid ? idx : beg];
        float du = valid ? dis[u] : 0.f;
        int cnt = end - j0; if (cnt > 64) cnt = 64;
        int pairs = (cnt + 1) >> 1;
        for (int t = 0; t < pairs; t++) {
            int srcl = 2 * t + p;
            int uu = __shfl(u, srcl);
            float dd = __shfl(du, srcl);
            uint2 hv = *(const uint2*)(h + (size_t)uu * H_DIM + 4 * c);
            a0 += dd * bflo(hv.x);
            a1 += dd * bfhi(hv.x);
            a2 += dd * bflo(hv.y);
            a3 += dd * bfhi(hv.y);
        }
    }
    a0 += __shfl_xor(a0, 32);
    a1 += __shfl_xor(a1, 32);
    a2 += __shfl_xor(a2, 32);
    a3 += __shfl_xor(a3, 32);
    float dv = dis[wv];
    floatx4 bb = *(const floatx4*)(b1 + 4 * c);
    float h0 = fmaxf(a0 * dv + bb[0], 0.f);
    float h1 = fmaxf(a1 * dv + bb[1], 0.f);
    float h2v = fmaxf(a2 * dv + bb[2], 0.f);
    float h3 = fmaxf(a3 * dv + bb[3], 0.f);
    floatx4 wA = *(const floatx4*)(W2 + 8 * c);
    floatx4 wB = *(const floatx4*)(W2 + 8 * c + 4);
    float p0 = h0 * wA[0] + h1 * wA[2] + h2v * wB[0] + h3 * wB[2];
    float p1 = h0 * wA[1] + h1 * wA[3] + h2v * wB[1] + h3 * wB[3];
#pragma unroll
    for (int m = 16; m >= 1; m >>= 1) {
        p0 += __shfl_xor(p0, m);
        p1 += __shfl_xor(p1, m);
    }
    if (lane == 0) {
        h2[(size_t)wv * 2]     = p0;
        h2[(size_t)wv * 2 + 1] = p1;
    }
}

// ---------- Layer-2 aggregation (CSR gather, incl. self loop) + bias + softmax ----------
__global__ void k_agg2sm(const int* __restrict__ csr, const int* __restrict__ offs,
                         const float* __restrict__ dis, const float* __restrict__ h2,
                         const float* __restrict__ b2, float* __restrict__ out, int N) {
    int i = blockIdx.x * blockDim.x + threadIdx.x;
    if (i >= N) return;
    int beg = offs[i], end = offs[i + 1];
    float a0 = 0.f, a1 = 0.f;
    for (int j = beg; j < end; j++) {
        int u = csr[j];
        float w = dis[u];
        float2 hv = *(const float2*)(h2 + (size_t)u * 2);
        a0 += w * hv.x;
        a1 += w * hv.y;
    }
    float dv = dis[i];
    float o0 = a0 * dv + b2[0];
    float o1 = a1 * dv + b2[1];
    float m = fmaxf(o0, o1);
    float e0 = __expf(o0 - m), e1 = __expf(o1 - m);
    float inv = 1.f / (e0 + e1);
    float2 r; r.x = e0 * inv; r.y = e1 * inv;
    *(float2*)(out + (size_t)i * 2) = r;
}

extern "C" void kernel_launch(void* const* d_in, const int* in_sizes, int n_in,
                              void* d_out, int out_size, void* d_ws, size_t ws_size,
                              hipStream_t stream) {
    const float* x  = (const float*)d_in[0];
    const int*   ei = (const int*)d_in[1];
    const float* W1 = (const float*)d_in[2];
    const float* b1 = (const float*)d_in[3];
    const float* W2 = (const float*)d_in[4];
    const float* b2 = (const float*)d_in[5];
    int N = in_sizes[0] / F_IN;
    int E = in_sizes[1] / 2;
    int NB = (N + (1 << BSHIFT) - 1) >> BSHIFT;

    char* p = (char*)d_ws;
    auto alloc = [&](size_t bytes) {
        void* q = (void*)p;
        p += (bytes + 255) & ~(size_t)255;
        return q;
    };
    int* cnt              = (int*)alloc((size_t)N * 4);
    int* offs             = (int*)alloc((size_t)(N + 1) * 4);
    int* cursor           = (int*)alloc((size_t)N * 4);
    int* csr              = (int*)alloc((size_t)(N + E) * 4);
    float* dis            = (float*)alloc((size_t)N * 4);
    unsigned short* W1B   = (unsigned short*)alloc((size_t)F_IN * H_DIM * 2);
    unsigned short* h     = (unsigned short*)alloc((size_t)N * H_DIM * 2);
    float* h2             = (float*)alloc((size_t)N * 2 * 4);
    int* ebase            = (int*)alloc((size_t)(NB + 1) * 4);
    int* bcur             = (int*)alloc((size_t)NB * 4);
    uint2* binned         = (uint2*)alloc((size_t)E * 8);
    float* out            = (float*)d_out;

    k_init_cnt<<<(N + 255) / 256, 256, 0, stream>>>(cnt, N);
    k_w1b<<<(8 * 24 * 64 + 255) / 256, 256, 0, stream>>>(W1, W1B);
    k_count<<<(E + 255) / 256, 256, 0, stream>>>(ei, E, N, cnt);
    k_scan<<<1, 1024, 0, stream>>>(cnt, offs, N);
    k_bbase<<<(NB + 256) / 256, 256, 0, stream>>>(offs, ebase, bcur, N, NB);
    k_prep<<<(N + 255) / 256, 256, 0, stream>>>(cnt, offs, csr, cursor, dis, N);
    k_bin<<<(E + 255) / 256, 256, 0, stream>>>(ei, E, N, bcur, binned);
    k_fill2<<<NB, 256, 0, stream>>>(binned, ebase, cursor, csr);
    k_gemm1<<<(N + 15) / 16, 256, 0, stream>>>(x, W1B, h, N);
    k_agg1<<<(N + 3) / 4, 256, 0, stream>>>(h, csr, offs, dis, b1, W2, h2, N);
    k_agg2sm<<<(N + 255) / 256, 256, 0, stream>>>(csr, offs, dis, h2, b2, out, N);
}

// Round 5
// 563.915 us; speedup vs baseline: 1.6279x; 1.6279x over previous
//
#include <hip/hip_runtime.h>
#include <hip/hip_bf16.h>
#include <stdint.h>

#define F_IN 768
#define H_DIM 128

typedef __attribute__((ext_vector_type(8))) short short8;
typedef __attribute__((ext_vector_type(4))) float floatx4;

__device__ __forceinline__ unsigned short f2bf(float f) {
    union { float f; unsigned u; } v; v.f = f;
    unsigned r = v.u + 0x7fff + ((v.u >> 16) & 1);   // RNE
    return (unsigned short)(r >> 16);
}
__device__ __forceinline__ float bflo(unsigned u) {
    union { unsigned u; float f; } v; v.u = u << 16;
    return v.f;
}
__device__ __forceinline__ float bfhi(unsigned u) {
    union { unsigned u; float f; } v; v.u = u & 0xffff0000u;
    return v.f;
}

// ---------- CSR build ----------
__global__ void k_init_cnt(int* __restrict__ cnt, int N) {
    int i = blockIdx.x * blockDim.x + threadIdx.x;
    if (i < N) cnt[i] = 1;  // self loop
}

// XCD-partitioned count: group g = blockIdx&7 handles dst range slice g.
// Each group streams the full dst list coalesced; its cnt slice (25KB)
// stays L2-local on one XCD (blockIdx%8 -> XCD round-robin heuristic).
__global__ __launch_bounds__(256) void k_count2(const int* __restrict__ ei, int E, int N,
                                                int* __restrict__ cnt) {
    int g = blockIdx.x & 7;
    int r = blockIdx.x >> 3;
    int nbg = gridDim.x >> 3;
    int span = (N + 7) >> 3;
    int lo = g * span, hi = min(lo + span, N);
    for (int e = r * 256 + threadIdx.x; e < E; e += nbg * 256) {
        int d = ei[E + e];
        d = min(max(d, 0), N - 1);
        if (d >= lo && d < hi) atomicAdd(&cnt[d], 1);
    }
}

__global__ __launch_bounds__(1024) void k_scan(const int* __restrict__ cnt,
                                               int* __restrict__ offs, int N) {
    __shared__ int sdata[1024];
    int t = threadIdx.x;
    int chunk = (N + 1023) >> 10;
    int beg = t * chunk, end = min(beg + chunk, N);
    int s = 0;
    for (int i = beg; i < end; i++) s += cnt[i];
    sdata[t] = s;
    __syncthreads();
    for (int off = 1; off < 1024; off <<= 1) {
        int v = (t >= off) ? sdata[t - off] : 0;
        __syncthreads();
        sdata[t] += v;
        __syncthreads();
    }
    int excl = sdata[t] - s;
    int run = excl;
    for (int i = beg; i < end; i++) { offs[i] = run; run += cnt[i]; }
    if (t == 1023) offs[N] = sdata[1023];
}

__global__ void k_prep(const int* __restrict__ cnt, const int* __restrict__ offs,
                       int* __restrict__ csr, int* __restrict__ cursor,
                       float* __restrict__ dis, int N) {
    int i = blockIdx.x * blockDim.x + threadIdx.x;
    if (i < N) {
        int o = offs[i];
        csr[o] = i;             // self loop entry first
        cursor[i] = o + 1;
        dis[i] = rsqrtf((float)cnt[i]);
    }
}

// XCD-partitioned fill: same grouping; group g's csr slice (~825KB) stays
// in one XCD's L2, so scattered csr writes coalesce before writeback.
__global__ __launch_bounds__(256) void k_fill3(const int* __restrict__ ei, int E, int N,
                                               int* __restrict__ cursor,
                                               int* __restrict__ csr) {
    int g = blockIdx.x & 7;
    int r = blockIdx.x >> 3;
    int nbg = gridDim.x >> 3;
    int span = (N + 7) >> 3;
    int lo = g * span, hi = min(lo + span, N);
    for (int e = r * 256 + threadIdx.x; e < E; e += nbg * 256) {
        int s = ei[e];
        int d = ei[E + e];
        d = min(max(d, 0), N - 1);
        if (d >= lo && d < hi) {
            s = min(max(s, 0), N - 1);
            int pos = atomicAdd(&cursor[d], 1);
            csr[pos] = s;
        }
    }
}

// ---------- W1 -> bf16 in MFMA B-fragment order ----------
// W1B[f][kb][lane][j]  (f<8, kb<24, lane<64, j<8), flat idx = ((f*24+kb)*64+lane)*8+j
// maps to B[k][n] with n = f*16 + (lane&15), k = kb*32 + (lane>>4)*8 + j
__global__ void k_w1b(const float* __restrict__ W1, unsigned short* __restrict__ W1B) {
    int t = blockIdx.x * blockDim.x + threadIdx.x;   // one thread per 8-elem group
    if (t >= 8 * 24 * 64) return;
    int lane = t & 63;
    int kb = (t >> 6) % 24;
    int f  = (t >> 6) / 24;
    int r = lane & 15, quad = lane >> 4;
    int col = f * 16 + r;
    int k0 = kb * 32 + quad * 8;
    unsigned short* o = W1B + (size_t)t * 8;
#pragma unroll
    for (int j = 0; j < 8; j++) o[j] = f2bf(W1[(size_t)(k0 + j) * H_DIM + col]);
}

// ---------- GEMM1: h = bf16(x @ W1), MFMA 16x16x32 bf16 ----------
#define A_STRIDE 776
__global__ __launch_bounds__(256) void k_gemm1(const float* __restrict__ x,
                                               const unsigned short* __restrict__ W1B,
                                               unsigned short* __restrict__ h, int N) {
    __shared__ unsigned short As[16 * A_STRIDE];
    int rowblk = blockIdx.x * 16;

#pragma unroll
    for (int j = 0; j < 12; j++) {
        int seg = j * 256 + threadIdx.x;          // 0..3071, 192 segs/row
        int row = seg / 192;
        int col = (seg - row * 192) * 4;
        int srow = min(rowblk + row, N - 1);
        floatx4 v = *(const floatx4*)(x + (size_t)srow * F_IN + col);
        uint2 w;
        w.x = (unsigned)f2bf(v[0]) | ((unsigned)f2bf(v[1]) << 16);
        w.y = (unsigned)f2bf(v[2]) | ((unsigned)f2bf(v[3]) << 16);
        *(uint2*)(&As[row * A_STRIDE + col]) = w;
    }
    __syncthreads();

    int wv = threadIdx.x >> 6;
    int lane = threadIdx.x & 63;
    int quad = lane >> 4;
    int r = lane & 15;

    const unsigned short* bp = W1B + ((size_t)(2 * wv) * 24 * 512) + (size_t)lane * 8;
    const unsigned short* ap = As + r * A_STRIDE + quad * 8;

    floatx4 acc0 = (floatx4){0.f, 0.f, 0.f, 0.f};
    floatx4 acc1 = (floatx4){0.f, 0.f, 0.f, 0.f};
#pragma unroll
    for (int kb = 0; kb < 24; kb++) {
        short8 af = *(const short8*)(ap + kb * 32);
        short8 b0 = *(const short8*)(bp + kb * 512);
        short8 b1 = *(const short8*)(bp + 12288 + kb * 512);   // f+1 block
        acc0 = __builtin_amdgcn_mfma_f32_16x16x32_bf16(af, b0, acc0, 0, 0, 0);
        acc1 = __builtin_amdgcn_mfma_f32_16x16x32_bf16(af, b1, acc1, 0, 0, 0);
    }
    int c0 = (2 * wv) * 16 + r, c1 = (2 * wv + 1) * 16 + r;
#pragma unroll
    for (int i = 0; i < 4; i++) {
        int orow = rowblk + quad * 4 + i;
        if (orow < N) {
            h[(size_t)orow * H_DIM + c0] = f2bf(acc0[i]);
            h[(size_t)orow * H_DIM + c1] = f2bf(acc1[i]);
        }
    }
}

// ---------- Aggregation layer 1 + bias + relu + @W2 fused ----------
__global__ __launch_bounds__(256) void k_agg1(const unsigned short* __restrict__ h,
                                              const int* __restrict__ csr,
                                              const int* __restrict__ offs,
                                              const float* __restrict__ dis,
                                              const float* __restrict__ b1,
                                              const float* __restrict__ W2,
                                              float* __restrict__ h2, int N) {
    int wv = (blockIdx.x * blockDim.x + threadIdx.x) >> 6;
    if (wv >= N) return;
    int lane = threadIdx.x & 63;
    int c = lane & 31;
    int p = lane >> 5;
    int beg = offs[wv], end = offs[wv + 1];
    float a0 = 0.f, a1 = 0.f, a2 = 0.f, a3 = 0.f;
    for (int j0 = beg; j0 < end; j0 += 64) {
        int idx = j0 + lane;
        bool valid = idx < end;
        int u = csr[valid ? idx : beg];
        float du = valid ? dis[u] : 0.f;
        int cnt = end - j0; if (cnt > 64) cnt = 64;
        int pairs = (cnt + 1) >> 1;
        for (int t = 0; t < pairs; t++) {
            int srcl = 2 * t + p;
            int uu = __shfl(u, srcl);
            float dd = __shfl(du, srcl);
            uint2 hv = *(const uint2*)(h + (size_t)uu * H_DIM + 4 * c);
            a0 += dd * bflo(hv.x);
            a1 += dd * bfhi(hv.x);
            a2 += dd * bflo(hv.y);
            a3 += dd * bfhi(hv.y);
        }
    }
    a0 += __shfl_xor(a0, 32);
    a1 += __shfl_xor(a1, 32);
    a2 += __shfl_xor(a2, 32);
    a3 += __shfl_xor(a3, 32);
    float dv = dis[wv];
    floatx4 bb = *(const floatx4*)(b1 + 4 * c);
    float h0 = fmaxf(a0 * dv + bb[0], 0.f);
    float h1 = fmaxf(a1 * dv + bb[1], 0.f);
    float h2v = fmaxf(a2 * dv + bb[2], 0.f);
    float h3 = fmaxf(a3 * dv + bb[3], 0.f);
    floatx4 wA = *(const floatx4*)(W2 + 8 * c);
    floatx4 wB = *(const floatx4*)(W2 + 8 * c + 4);
    float p0 = h0 * wA[0] + h1 * wA[2] + h2v * wB[0] + h3 * wB[2];
    float p1 = h0 * wA[1] + h1 * wA[3] + h2v * wB[1] + h3 * wB[3];
#pragma unroll
    for (int m = 16; m >= 1; m >>= 1) {
        p0 += __shfl_xor(p0, m);
        p1 += __shfl_xor(p1, m);
    }
    if (lane == 0) {
        h2[(size_t)wv * 2]     = p0;
        h2[(size_t)wv * 2 + 1] = p1;
    }
}

// ---------- Layer-2 aggregation (CSR gather, incl. self loop) + bias + softmax ----------
__global__ void k_agg2sm(const int* __restrict__ csr, const int* __restrict__ offs,
                         const float* __restrict__ dis, const float* __restrict__ h2,
                         const float* __restrict__ b2, float* __restrict__ out, int N) {
    int i = blockIdx.x * blockDim.x + threadIdx.x;
    if (i >= N) return;
    int beg = offs[i], end = offs[i + 1];
    float a0 = 0.f, a1 = 0.f;
    for (int j = beg; j < end; j++) {
        int u = csr[j];
        float w = dis[u];
        float2 hv = *(const float2*)(h2 + (size_t)u * 2);
        a0 += w * hv.x;
        a1 += w * hv.y;
    }
    float dv = dis[i];
    float o0 = a0 * dv + b2[0];
    float o1 = a1 * dv + b2[1];
    float m = fmaxf(o0, o1);
    float e0 = __expf(o0 - m), e1 = __expf(o1 - m);
    float inv = 1.f / (e0 + e1);
    float2 r; r.x = e0 * inv; r.y = e1 * inv;
    *(float2*)(out + (size_t)i * 2) = r;
}

extern "C" void kernel_launch(void* const* d_in, const int* in_sizes, int n_in,
                              void* d_out, int out_size, void* d_ws, size_t ws_size,
                              hipStream_t stream) {
    const float* x  = (const float*)d_in[0];
    const int*   ei = (const int*)d_in[1];
    const float* W1 = (const float*)d_in[2];
    const float* b1 = (const float*)d_in[3];
    const float* W2 = (const float*)d_in[4];
    const float* b2 = (const float*)d_in[5];
    int N = in_sizes[0] / F_IN;
    int E = in_sizes[1] / 2;

    char* p = (char*)d_ws;
    auto alloc = [&](size_t bytes) {
        void* q = (void*)p;
        p += (bytes + 255) & ~(size_t)255;
        return q;
    };
    int* cnt              = (int*)alloc((size_t)N * 4);
    int* offs             = (int*)alloc((size_t)(N + 1) * 4);
    int* cursor           = (int*)alloc((size_t)N * 4);
    int* csr              = (int*)alloc((size_t)(N + E) * 4);
    float* dis            = (float*)alloc((size_t)N * 4);
    unsigned short* W1B   = (unsigned short*)alloc((size_t)F_IN * H_DIM * 2);
    unsigned short* h     = (unsigned short*)alloc((size_t)N * H_DIM * 2);
    float* h2             = (float*)alloc((size_t)N * 2 * 4);
    float* out            = (float*)d_out;

    k_init_cnt<<<(N + 255) / 256, 256, 0, stream>>>(cnt, N);
    k_w1b<<<(8 * 24 * 64 + 255) / 256, 256, 0, stream>>>(W1, W1B);
    k_count2<<<2048, 256, 0, stream>>>(ei, E, N, cnt);
    k_scan<<<1, 1024, 0, stream>>>(cnt, offs, N);
    k_prep<<<(N + 255) / 256, 256, 0, stream>>>(cnt, offs, csr, cursor, dis, N);
    k_fill3<<<2048, 256, 0, stream>>>(ei, E, N, cursor, csr);
    k_gemm1<<<(N + 15) / 16, 256, 0, stream>>>(x, W1B, h, N);
    k_agg1<<<(N + 3) / 4, 256, 0, stream>>>(h, csr, offs, dis, b1, W2, h2, N);
    k_agg2sm<<<(N + 255) / 256, 256, 0, stream>>>(csr, offs, dis, h2, b2, out, N);
}

// Round 6
// 550.096 us; speedup vs baseline: 1.6688x; 1.0251x over previous
//
#include <hip/hip_runtime.h>
#include <hip/hip_bf16.h>
#include <stdint.h>

#define F_IN 768
#define H_DIM 128

typedef __attribute__((ext_vector_type(8))) short short8;
typedef __attribute__((ext_vector_type(4))) float floatx4;

__device__ __forceinline__ unsigned short f2bf(float f) {
    union { float f; unsigned u; } v; v.f = f;
    unsigned r = v.u + 0x7fff + ((v.u >> 16) & 1);   // RNE
    return (unsigned short)(r >> 16);
}
__device__ __forceinline__ float bflo(unsigned u) {
    union { unsigned u; float f; } v; v.u = u << 16;
    return v.f;
}
__device__ __forceinline__ float bfhi(unsigned u) {
    union { unsigned u; float f; } v; v.u = u & 0xffff0000u;
    return v.f;
}

// ---------- fused: cnt init + W1 -> bf16 MFMA-fragment reorder ----------
// W1B[f][kb][lane][j]: n = f*16 + (lane&15), k = kb*32 + (lane>>4)*8 + j
__global__ void k_init(int* __restrict__ cnt, int N,
                       const float* __restrict__ W1, unsigned short* __restrict__ W1B) {
    int t = blockIdx.x * blockDim.x + threadIdx.x;
    if (t < N) cnt[t] = 1;  // self loop
    if (t < 8 * 24 * 64) {
        int lane = t & 63;
        int kb = (t >> 6) % 24;
        int f  = (t >> 6) / 24;
        int r = lane & 15, quad = lane >> 4;
        int col = f * 16 + r;
        int k0 = kb * 32 + quad * 8;
        unsigned short* o = W1B + (size_t)t * 8;
#pragma unroll
        for (int j = 0; j < 8; j++) o[j] = f2bf(W1[(size_t)(k0 + j) * H_DIM + col]);
    }
}

// XCD-partitioned count: group g = blockIdx&7 handles dst range slice g.
__global__ __launch_bounds__(256) void k_count2(const int* __restrict__ ei, int E, int N,
                                                int* __restrict__ cnt) {
    int g = blockIdx.x & 7;
    int r = blockIdx.x >> 3;
    int nbg = gridDim.x >> 3;
    int span = (N + 7) >> 3;
    int lo = g * span, hi = min(lo + span, N);
    for (int e = r * 256 + threadIdx.x; e < E; e += nbg * 256) {
        int d = ei[E + e];
        d = min(max(d, 0), N - 1);
        if (d >= lo && d < hi) atomicAdd(&cnt[d], 1);
    }
}

__global__ __launch_bounds__(1024) void k_scan(const int* __restrict__ cnt,
                                               int* __restrict__ offs, int N) {
    __shared__ int sdata[1024];
    int t = threadIdx.x;
    int chunk = (N + 1023) >> 10;
    int beg = t * chunk, end = min(beg + chunk, N);
    int s = 0;
    for (int i = beg; i < end; i++) s += cnt[i];
    sdata[t] = s;
    __syncthreads();
    for (int off = 1; off < 1024; off <<= 1) {
        int v = (t >= off) ? sdata[t - off] : 0;
        __syncthreads();
        sdata[t] += v;
        __syncthreads();
    }
    int excl = sdata[t] - s;
    int run = excl;
    for (int i = beg; i < end; i++) { offs[i] = run; run += cnt[i]; }
    if (t == 1023) offs[N] = sdata[1023];
}

__global__ void k_prep(const int* __restrict__ cnt, const int* __restrict__ offs,
                       int* __restrict__ csr, int* __restrict__ cursor,
                       float* __restrict__ dis, int N) {
    int i = blockIdx.x * blockDim.x + threadIdx.x;
    if (i < N) {
        int o = offs[i];
        csr[o] = i;             // self loop entry first
        cursor[i] = o + 1;
        dis[i] = rsqrtf((float)cnt[i]);
    }
}

// XCD-partitioned fill
__global__ __launch_bounds__(256) void k_fill3(const int* __restrict__ ei, int E, int N,
                                               int* __restrict__ cursor,
                                               int* __restrict__ csr) {
    int g = blockIdx.x & 7;
    int r = blockIdx.x >> 3;
    int nbg = gridDim.x >> 3;
    int span = (N + 7) >> 3;
    int lo = g * span, hi = min(lo + span, N);
    for (int e = r * 256 + threadIdx.x; e < E; e += nbg * 256) {
        int s = ei[e];
        int d = ei[E + e];
        d = min(max(d, 0), N - 1);
        if (d >= lo && d < hi) {
            s = min(max(s, 0), N - 1);
            int pos = atomicAdd(&cursor[d], 1);
            csr[pos] = s;
        }
    }
}

// ---------- GEMM1: h = bf16(x @ W1), 32 rows/block, 4 waves ----------
// A_STRIDE=780 shorts -> 390 words/row, 390%32=6 -> 16 r-values hit 16
// distinct banks (conflict-free ds_read_b128). Wave w: cols f=2w,2w+1,
// both 16-row tiles -> W1B fragments reused across 2 row-tiles.
#define A_STRIDE 780
__global__ __launch_bounds__(256) void k_gemm1(const float* __restrict__ x,
                                               const unsigned short* __restrict__ W1B,
                                               unsigned short* __restrict__ h, int N) {
    __shared__ unsigned short As[32 * A_STRIDE];
    int rowblk = blockIdx.x * 32;

    // stage 32 rows of x into LDS as bf16: 6144 float4 segs, 24/thread
#pragma unroll
    for (int j = 0; j < 24; j++) {
        int seg = j * 256 + threadIdx.x;
        int row = seg / 192;
        int col = (seg - row * 192) * 4;
        int srow = min(rowblk + row, N - 1);
        floatx4 v = *(const floatx4*)(x + (size_t)srow * F_IN + col);
        uint2 w;
        w.x = (unsigned)f2bf(v[0]) | ((unsigned)f2bf(v[1]) << 16);
        w.y = (unsigned)f2bf(v[2]) | ((unsigned)f2bf(v[3]) << 16);
        *(uint2*)(&As[row * A_STRIDE + col]) = w;
    }
    __syncthreads();

    int wv = threadIdx.x >> 6;
    int lane = threadIdx.x & 63;
    int quad = lane >> 4;
    int r = lane & 15;

    const unsigned short* bp = W1B + ((size_t)(2 * wv) * 24 * 512) + (size_t)lane * 8;
    const unsigned short* ap0 = As + r * A_STRIDE + quad * 8;
    const unsigned short* ap1 = As + (16 + r) * A_STRIDE + quad * 8;

    floatx4 acc00 = (floatx4){0.f, 0.f, 0.f, 0.f};   // rt0, f0
    floatx4 acc01 = (floatx4){0.f, 0.f, 0.f, 0.f};   // rt0, f1
    floatx4 acc10 = (floatx4){0.f, 0.f, 0.f, 0.f};   // rt1, f0
    floatx4 acc11 = (floatx4){0.f, 0.f, 0.f, 0.f};   // rt1, f1
#pragma unroll
    for (int kb = 0; kb < 24; kb++) {
        short8 af0 = *(const short8*)(ap0 + kb * 32);
        short8 af1 = *(const short8*)(ap1 + kb * 32);
        short8 b0 = *(const short8*)(bp + kb * 512);
        short8 b1 = *(const short8*)(bp + 12288 + kb * 512);
        acc00 = __builtin_amdgcn_mfma_f32_16x16x32_bf16(af0, b0, acc00, 0, 0, 0);
        acc01 = __builtin_amdgcn_mfma_f32_16x16x32_bf16(af0, b1, acc01, 0, 0, 0);
        acc10 = __builtin_amdgcn_mfma_f32_16x16x32_bf16(af1, b0, acc10, 0, 0, 0);
        acc11 = __builtin_amdgcn_mfma_f32_16x16x32_bf16(af1, b1, acc11, 0, 0, 0);
    }
    int c0 = (2 * wv) * 16 + r, c1 = (2 * wv + 1) * 16 + r;
#pragma unroll
    for (int i = 0; i < 4; i++) {
        int orow0 = rowblk + quad * 4 + i;
        int orow1 = orow0 + 16;
        if (orow0 < N) {
            h[(size_t)orow0 * H_DIM + c0] = f2bf(acc00[i]);
            h[(size_t)orow0 * H_DIM + c1] = f2bf(acc01[i]);
        }
        if (orow1 < N) {
            h[(size_t)orow1 * H_DIM + c0] = f2bf(acc10[i]);
            h[(size_t)orow1 * H_DIM + c1] = f2bf(acc11[i]);
        }
    }
}

// ---------- Aggregation layer 1 + bias + relu + @W2 fused ----------
// one wave per node; lane = 16p + c: lane holds feats 8c..8c+7 of neighbor
// slot p; 4 neighbors per inner iteration via uint4 (16B) loads.
__global__ __launch_bounds__(256) void k_agg1(const unsigned short* __restrict__ h,
                                              const int* __restrict__ csr,
                                              const int* __restrict__ offs,
                                              const float* __restrict__ dis,
                                              const float* __restrict__ b1,
                                              const float* __restrict__ W2,
                                              float* __restrict__ h2, int N) {
    int wv = (blockIdx.x * blockDim.x + threadIdx.x) >> 6;
    if (wv >= N) return;
    int lane = threadIdx.x & 63;
    int c = lane & 15;
    int p = lane >> 4;
    int beg = offs[wv], end = offs[wv + 1];
    float a0 = 0.f, a1 = 0.f, a2 = 0.f, a3 = 0.f;
    float a4 = 0.f, a5 = 0.f, a6 = 0.f, a7 = 0.f;
    for (int j0 = beg; j0 < end; j0 += 64) {
        int idx = j0 + lane;
        bool valid = idx < end;
        int u = csr[valid ? idx : beg];
        float du = valid ? dis[u] : 0.f;
        int cnt = end - j0; if (cnt > 64) cnt = 64;
        int quads = (cnt + 3) >> 2;
        for (int t = 0; t < quads; t++) {
            int srcl = 4 * t + p;
            int uu = __shfl(u, srcl);
            float dd = __shfl(du, srcl);
            uint4 hv = *(const uint4*)(h + (size_t)uu * H_DIM + 8 * c);
            a0 += dd * bflo(hv.x); a1 += dd * bfhi(hv.x);
            a2 += dd * bflo(hv.y); a3 += dd * bfhi(hv.y);
            a4 += dd * bflo(hv.z); a5 += dd * bfhi(hv.z);
            a6 += dd * bflo(hv.w); a7 += dd * bfhi(hv.w);
        }
    }
    // sum the 4 neighbor-slot copies (lanes c, c+16, c+32, c+48)
    a0 += __shfl_xor(a0, 16); a0 += __shfl_xor(a0, 32);
    a1 += __shfl_xor(a1, 16); a1 += __shfl_xor(a1, 32);
    a2 += __shfl_xor(a2, 16); a2 += __shfl_xor(a2, 32);
    a3 += __shfl_xor(a3, 16); a3 += __shfl_xor(a3, 32);
    a4 += __shfl_xor(a4, 16); a4 += __shfl_xor(a4, 32);
    a5 += __shfl_xor(a5, 16); a5 += __shfl_xor(a5, 32);
    a6 += __shfl_xor(a6, 16); a6 += __shfl_xor(a6, 32);
    a7 += __shfl_xor(a7, 16); a7 += __shfl_xor(a7, 32);

    float dv = dis[wv];
    floatx4 bb0 = *(const floatx4*)(b1 + 8 * c);
    floatx4 bb1 = *(const floatx4*)(b1 + 8 * c + 4);
    float h0 = fmaxf(a0 * dv + bb0[0], 0.f);
    float h1 = fmaxf(a1 * dv + bb0[1], 0.f);
    float h2a = fmaxf(a2 * dv + bb0[2], 0.f);
    float h3 = fmaxf(a3 * dv + bb0[3], 0.f);
    float h4 = fmaxf(a4 * dv + bb1[0], 0.f);
    float h5 = fmaxf(a5 * dv + bb1[1], 0.f);
    float h6 = fmaxf(a6 * dv + bb1[2], 0.f);
    float h7 = fmaxf(a7 * dv + bb1[3], 0.f);
    // W2 rows 8c..8c+7 (2 floats each)
    const float* w2p = W2 + 16 * c;
    floatx4 wA = *(const floatx4*)(w2p);
    floatx4 wB = *(const floatx4*)(w2p + 4);
    floatx4 wC = *(const floatx4*)(w2p + 8);
    floatx4 wD = *(const floatx4*)(w2p + 12);
    float p0 = h0 * wA[0] + h1 * wA[2] + h2a * wB[0] + h3 * wB[2]
             + h4 * wC[0] + h5 * wC[2] + h6 * wD[0] + h7 * wD[2];
    float p1 = h0 * wA[1] + h1 * wA[3] + h2a * wB[1] + h3 * wB[3]
             + h4 * wC[1] + h5 * wC[3] + h6 * wD[1] + h7 * wD[3];
#pragma unroll
    for (int m = 8; m >= 1; m >>= 1) {
        p0 += __shfl_xor(p0, m);
        p1 += __shfl_xor(p1, m);
    }
    if (lane == 0) {
        h2[(size_t)wv * 2]     = p0;
        h2[(size_t)wv * 2 + 1] = p1;
    }
}

// ---------- Layer-2 aggregation + bias + softmax: 16 lanes per node ----------
__global__ __launch_bounds__(256) void k_agg2sm(const int* __restrict__ csr,
                                                const int* __restrict__ offs,
                                                const float* __restrict__ dis,
                                                const float* __restrict__ h2,
                                                const float* __restrict__ b2,
                                                float* __restrict__ out, int N) {
    int i = (blockIdx.x * blockDim.x + threadIdx.x) >> 4;
    if (i >= N) return;
    int l = threadIdx.x & 15;
    int beg = offs[i], end = offs[i + 1];
    float a0 = 0.f, a1 = 0.f;
    for (int j = beg + l; j < end; j += 16) {
        int u = csr[j];
        float w = dis[u];
        float2 hv = *(const float2*)(h2 + (size_t)u * 2);
        a0 += w * hv.x;
        a1 += w * hv.y;
    }
#pragma unroll
    for (int m = 8; m >= 1; m >>= 1) {
        a0 += __shfl_xor(a0, m);
        a1 += __shfl_xor(a1, m);
    }
    if (l == 0) {
        float dv = dis[i];
        float o0 = a0 * dv + b2[0];
        float o1 = a1 * dv + b2[1];
        float m = fmaxf(o0, o1);
        float e0 = __expf(o0 - m), e1 = __expf(o1 - m);
        float inv = 1.f / (e0 + e1);
        float2 r; r.x = e0 * inv; r.y = e1 * inv;
        *(float2*)(out + (size_t)i * 2) = r;
    }
}

extern "C" void kernel_launch(void* const* d_in, const int* in_sizes, int n_in,
                              void* d_out, int out_size, void* d_ws, size_t ws_size,
                              hipStream_t stream) {
    const float* x  = (const float*)d_in[0];
    const int*   ei = (const int*)d_in[1];
    const float* W1 = (const float*)d_in[2];
    const float* b1 = (const float*)d_in[3];
    const float* W2 = (const float*)d_in[4];
    const float* b2 = (const float*)d_in[5];
    int N = in_sizes[0] / F_IN;
    int E = in_sizes[1] / 2;

    char* p = (char*)d_ws;
    auto alloc = [&](size_t bytes) {
        void* q = (void*)p;
        p += (bytes + 255) & ~(size_t)255;
        return q;
    };
    int* cnt              = (int*)alloc((size_t)N * 4);
    int* offs             = (int*)alloc((size_t)(N + 1) * 4);
    int* cursor           = (int*)alloc((size_t)N * 4);
    int* csr              = (int*)alloc((size_t)(N + E) * 4);
    float* dis            = (float*)alloc((size_t)N * 4);
    unsigned short* W1B   = (unsigned short*)alloc((size_t)F_IN * H_DIM * 2);
    unsigned short* h     = (unsigned short*)alloc((size_t)N * H_DIM * 2);
    float* h2             = (float*)alloc((size_t)N * 2 * 4);
    float* out            = (float*)d_out;

    k_init<<<(N + 255) / 256, 256, 0, stream>>>(cnt, N, W1, W1B);
    k_count2<<<2048, 256, 0, stream>>>(ei, E, N, cnt);
    k_scan<<<1, 1024, 0, stream>>>(cnt, offs, N);
    k_prep<<<(N + 255) / 256, 256, 0, stream>>>(cnt, offs, csr, cursor, dis, N);
    k_fill3<<<2048, 256, 0, stream>>>(ei, E, N, cursor, csr);
    k_gemm1<<<(N + 31) / 32, 256, 0, stream>>>(x, W1B, h, N);
    k_agg1<<<(N + 3) / 4, 256, 0, stream>>>(h, csr, offs, dis, b1, W2, h2, N);
    k_agg2sm<<<(N * 16 + 255) / 256, 256, 0, stream>>>(csr, offs, dis, h2, b2, out, N);
}